// Round 3
// baseline (374.668 us; speedup 1.0000x reference)
//
#include <hip/hip_runtime.h>

#define BB 16
#define CC 128
#define NN 16384
#define BN_EPS 1e-5f

typedef unsigned short u16;
typedef short short8 __attribute__((ext_vector_type(8)));
typedef float floatx4 __attribute__((ext_vector_type(4)));

__device__ inline float b2f(u16 u) {
    union { unsigned int i; float f; } c; c.i = ((unsigned int)u) << 16; return c.f;
}
__device__ inline u16 f2b(float f) {  // round-to-nearest-even bf16
    union { float f; unsigned int i; } c; c.f = f;
    unsigned int r = c.i + 0x7fffu + ((c.i >> 16) & 1u);
    return (u16)(r >> 16);
}
// HW packed fp32->bf16 (RNE), 1 inst for 2 values: dst.lo16=bf16(a), dst.hi16=bf16(b)
__device__ inline unsigned cvt_pk_bf16(float a, float b) {
    unsigned r;
    asm("v_cvt_pk_bf16_f32 %0, %1, %2" : "=v"(r) : "v"(a), "v"(b));
    return r;
}

// ---------------------------------------------------------------------------
// K1: Gram via split-bf16 MFMA (E ~= XhXh^T + XlXh^T + XhXl^T).
// Round-3: NO Gram atomics — each block writes its 128x128 fp32 tile to a
// private partials[b][slab] region with plain stores (the 8.4M device-scope
// atomicAdds were ~28us of RMW serialization; r0->r1 delta tracked atomic
// count exactly). k_reduce sums the 32 slabs. Conversions use
// v_cvt_pk_bf16_f32 (1 inst / 2 floats).
// One block = full 128x128 tile over a K-slab of 512; 8 waves (4 row-pairs x
// 2 col-halves); register-prefetch pipeline with raw s_barrier (vmcnt NOT
// drained across barriers). grid 512 = 16 b x 32 slabs.
// ---------------------------------------------------------------------------
#define K1_LD 72   // 64 + 8 halfs pad (144 B rows, 16B-aligned)
__global__ __launch_bounds__(512, 4) void k_gram(const float* __restrict__ x,
                                                 float* __restrict__ partials,
                                                 float* __restrict__ S)
{
    __shared__ u16 th[128 * K1_LD];
    __shared__ u16 tl[128 * K1_LD];
    const int rbid = blockIdx.x;              // 0..511
    const int xcd  = rbid & 7;                // dispatch round-robins XCDs
    const int li   = rbid >> 3;               // 0..63 within XCD
    const int b    = xcd * 2 + (li >> 5);     // 2 batches per XCD
    const int slab = li & 31;
    const int k0   = slab * 512;              // K-slab of 512
    const int t    = threadIdx.x;
    const int w = t >> 6, lane = t & 63, quad = lane >> 4, colL = lane & 15;
    const int w2 = w >> 1;                    // row-pair group (0..3)
    const int chf = w & 1;                    // col half (0..1)

    floatx4 acc[2][4];
#pragma unroll
    for (int rt = 0; rt < 2; ++rt)
#pragma unroll
        for (int ct = 0; ct < 4; ++ct) acc[rt][ct] = {0.f, 0.f, 0.f, 0.f};
    float rs[4];
#pragma unroll
    for (int it = 0; it < 4; ++it) rs[it] = 0.f;

    const float* xb = x + (size_t)b * CC * NN;
    const int rrow = t >> 4;        // thread's fixed row residue (0..31)
    const int c4   = t & 15;        // thread's fixed col slot

    // prologue: stage-0 loads into registers
    float4 v[4];
#pragma unroll
    for (int it = 0; it < 4; ++it)
        v[it] = *(const float4*)(xb + (size_t)(it * 32 + rrow) * NN + k0 + c4 * 4);

    const int arow0 = w2 * 32 + colL;         // this wave's A rows
    for (int s = 0; s < 8; ++s) {
        // convert + LDS write current stage; issue next stage's loads in the
        // same loop so they fly across both barriers + the MFMA phase
#pragma unroll
        for (int it = 0; it < 4; ++it) {
            const int row = it * 32 + rrow;
            float4 vv = v[it];
            if (s < 7)
                v[it] = *(const float4*)(xb + (size_t)row * NN + k0 + (s + 1) * 64 + c4 * 4);
            unsigned hx = cvt_pk_bf16(vv.x, vv.y);
            unsigned hy = cvt_pk_bf16(vv.z, vv.w);
            union { unsigned u; float f; } u0, u1, u2, u3;
            u0.u = hx << 16; u1.u = hx & 0xffff0000u;
            u2.u = hy << 16; u3.u = hy & 0xffff0000u;
            uint2 hv, lv;
            hv.x = hx; hv.y = hy;
            lv.x = cvt_pk_bf16(vv.x - u0.f, vv.y - u1.f);
            lv.y = cvt_pk_bf16(vv.z - u2.f, vv.w - u3.f);
            *(uint2*)&th[row * K1_LD + c4 * 4] = hv;
            *(uint2*)&tl[row * K1_LD + c4 * 4] = lv;
            rs[it] += (vv.x + vv.y) + (vv.z + vv.w);
        }
        // raw barrier: ds_writes drained (lgkmcnt), vmcnt prefetch NOT drained
        asm volatile("s_waitcnt lgkmcnt(0)" ::: "memory");
        __builtin_amdgcn_s_barrier();

#pragma unroll
        for (int ks2 = 0; ks2 < 2; ++ks2) {
            const int kk = ks2 * 32 + quad * 8;
            short8 a0h = *(const short8*)&th[(arow0)      * K1_LD + kk];
            short8 a0l = *(const short8*)&tl[(arow0)      * K1_LD + kk];
            short8 a1h = *(const short8*)&th[(arow0 + 16) * K1_LD + kk];
            short8 a1l = *(const short8*)&tl[(arow0 + 16) * K1_LD + kk];
#pragma unroll
            for (int ct = 0; ct < 4; ++ct) {
                const int brow = chf * 64 + ct * 16 + colL;
                short8 bh = *(const short8*)&th[brow * K1_LD + kk];
                short8 bl = *(const short8*)&tl[brow * K1_LD + kk];
                acc[0][ct] = __builtin_amdgcn_mfma_f32_16x16x32_bf16(a0h, bh, acc[0][ct], 0, 0, 0);
                acc[1][ct] = __builtin_amdgcn_mfma_f32_16x16x32_bf16(a1h, bh, acc[1][ct], 0, 0, 0);
                acc[0][ct] = __builtin_amdgcn_mfma_f32_16x16x32_bf16(a0l, bh, acc[0][ct], 0, 0, 0);
                acc[1][ct] = __builtin_amdgcn_mfma_f32_16x16x32_bf16(a1l, bh, acc[1][ct], 0, 0, 0);
                acc[0][ct] = __builtin_amdgcn_mfma_f32_16x16x32_bf16(a0h, bl, acc[0][ct], 0, 0, 0);
                acc[1][ct] = __builtin_amdgcn_mfma_f32_16x16x32_bf16(a1h, bl, acc[1][ct], 0, 0, 0);
            }
        }
        // raw barrier: my ds_reads done before anyone overwrites the tile
        asm volatile("s_waitcnt lgkmcnt(0)" ::: "memory");
        __builtin_amdgcn_s_barrier();
    }

    // write full tile to this block's private partials region (plain stores)
    float* pb = partials + (size_t)(b * 32 + slab) * (CC * CC);
#pragma unroll
    for (int rt = 0; rt < 2; ++rt)
#pragma unroll
        for (int ct = 0; ct < 4; ++ct)
#pragma unroll
            for (int r = 0; r < 4; ++r) {
                int row = w2 * 32 + rt * 16 + quad * 4 + r;
                int col = chf * 64 + ct * 16 + colL;
                pb[row * CC + col] = acc[rt][ct][r];
            }

    // row-sums (atomic: tiny count, 128/block)
#pragma unroll
    for (int it = 0; it < 4; ++it) {
        float ps = rs[it];
#pragma unroll
        for (int off = 8; off > 0; off >>= 1) ps += __shfl_down(ps, off, 16);
        if (c4 == 0) atomicAdd(&S[b * CC + it * 32 + rrow], ps);
    }
}

// ---------------------------------------------------------------------------
// K1b: energy[b][i][j] = sum_slab partials[b][slab][i][j]
// grid 1024 x 256: thread owns 8 consecutive floats; 33.5 MB coalesced read.
// ---------------------------------------------------------------------------
__global__ __launch_bounds__(256) void k_reduce(const float* __restrict__ partials,
                                                float* __restrict__ energy)
{
    const size_t base = (size_t)blockIdx.x * 2048 + (size_t)threadIdx.x * 8;
    const size_t b    = base >> 14;           // /16384
    const size_t off  = base & 16383;
    const float* p = partials + b * (32 * (size_t)CC * CC) + off;
    float4 s0 = {0.f, 0.f, 0.f, 0.f};
    float4 s1 = {0.f, 0.f, 0.f, 0.f};
#pragma unroll 8
    for (int s = 0; s < 32; ++s) {
        float4 a = *(const float4*)(p + (size_t)s * (CC * CC));
        float4 c = *(const float4*)(p + (size_t)s * (CC * CC) + 4);
        s0.x += a.x; s0.y += a.y; s0.z += a.z; s0.w += a.w;
        s1.x += c.x; s1.y += c.y; s1.z += c.z; s1.w += c.w;
    }
    *(float4*)(energy + base)     = s0;
    *(float4*)(energy + base + 4) = s1;
}

// ---------------------------------------------------------------------------
// K2: per (b,i): att = softmax(-E[i,:]) (bf16-stored);
//     meanacc[i] += att . S[b,:];  e2acc[i] += att^T E att
// Round-3 rewrite: ONE WAVE per row, zero __syncthreads (old version had ~40
// barrier-tree syncs per tiny block). Shuffle reductions only; e2 via column
// accumulation (coalesced float2 row reads, one __shfl broadcast per j).
// grid 512 x 256 (4 waves/block, all rows of a block share b).
// ---------------------------------------------------------------------------
__global__ __launch_bounds__(256) void k_soft(const float* __restrict__ energy,
                                              const float* __restrict__ S,
                                              u16* __restrict__ attb,
                                              float* __restrict__ meanacc,
                                              float* __restrict__ e2acc)
{
    const int t = threadIdx.x;
    const int w = t >> 6, lane = t & 63;
    const int row = blockIdx.x * 4 + w;       // 0..2047
    const int b = row >> 7, i = row & 127;
    const float* E = energy + (size_t)b * CC * CC;

    // lane owns columns 2*lane, 2*lane+1
    float2 ev = *(const float2*)&E[i * CC + lane * 2];
    float m = fminf(ev.x, ev.y);
#pragma unroll
    for (int off = 1; off < 64; off <<= 1) m = fminf(m, __shfl_xor(m, off, 64));

    float a0 = expf(m - ev.x);
    float a1 = expf(m - ev.y);
    float z = a0 + a1;
#pragma unroll
    for (int off = 1; off < 64; off <<= 1) z += __shfl_xor(z, off, 64);

    u16 ab0 = f2b(a0 / z), ab1 = f2b(a1 / z);
    float at0 = b2f(ab0), at1 = b2f(ab1);     // bf16-rounded: consistent with K3
    *(unsigned*)&attb[((size_t)b * CC + i) * CC + lane * 2] =
        (unsigned)ab0 | ((unsigned)ab1 << 16);

    float2 sv = *(const float2*)&S[b * CC + lane * 2];
    float mp = at0 * sv.x + at1 * sv.y;
#pragma unroll
    for (int off = 1; off < 64; off <<= 1) mp += __shfl_xor(mp, off, 64);
    if (lane == 0) atomicAdd(&meanacc[i], mp);

    // e2 = sum_k att_k * (sum_j att_j E[j][k]): lane accumulates its 2 columns
    float c0 = 0.f, c1 = 0.f;
#pragma unroll 8
    for (int jj = 0; jj < 64; ++jj) {
        float aj0 = __shfl(at0, jj, 64);      // att[2*jj]
        float aj1 = __shfl(at1, jj, 64);      // att[2*jj+1]
        float2 r0 = *(const float2*)&E[(2 * jj) * CC + lane * 2];
        float2 r1 = *(const float2*)&E[(2 * jj + 1) * CC + lane * 2];
        c0 += aj0 * r0.x + aj1 * r1.x;
        c1 += aj0 * r0.y + aj1 * r1.y;
    }
    float e2s = at0 * c0 + at1 * c1;
#pragma unroll
    for (int off = 1; off < 64; off <<= 1) e2s += __shfl_xor(e2s, off, 64);
    if (lane == 0) atomicAdd(&e2acc[i], e2s);
}

// ---------------------------------------------------------------------------
// K3: out = alpha_c * (att @ q_bf16) + beta_c + x.
// q staged TRANSPOSED (n-major) via register 4x4 transpose, rotation-swizzled
// so B-fragments are aligned ds_read_b128. att A-frags read from global (L1/L2
// hot). Conversions via v_cvt_pk_bf16_f32. LDS 35.8 KB -> 4 blocks/CU.
// grid 2048 = 16 batches x 128 n-chunks of 128, block 256
// ---------------------------------------------------------------------------
#define K3_LD 136   // k-extent 128 + 8 pad (272 B rows, 16B-aligned)
__global__ __launch_bounds__(256, 4) void k_out(const float* __restrict__ x,
                                                const u16* __restrict__ attb,
                                                const float* __restrict__ meanacc,
                                                const float* __restrict__ e2acc,
                                                const float* __restrict__ gamma,
                                                const float* __restrict__ bnw,
                                                const float* __restrict__ bnb,
                                                float* __restrict__ out)
{
    __shared__ u16 qT[128 * K3_LD];   // [n][k], k-group rotated by n
    __shared__ float alpha[128];
    __shared__ float beta[128];
    const int b   = blockIdx.x >> 7;
    const int nn0 = (blockIdx.x & 127) * 128;
    const int t   = threadIdx.x;

    if (t < 128) {
        float g   = gamma[0];
        const float invBN = 1.f / (float)(BB * NN);
        float m   = g * meanacc[t] * invBN;
        float e2  = g * g * e2acc[t] * invBN;
        float var = e2 - m * m;
        float inv = rsqrtf(var + BN_EPS);
        float wv  = bnw[t];
        alpha[t] = g * wv * inv;
        beta[t]  = bnb[t] - m * wv * inv;
    }

    const float* xb = x + (size_t)b * CC * NN + nn0;
    const int n0 = (t & 31) * 4;
#pragma unroll
    for (int rep = 0; rep < 4; ++rep) {
        const int c0 = ((t >> 5) + rep * 8) * 4;   // k-rows c0..c0+3
        float4 f0 = *(const float4*)(xb + (size_t)(c0 + 0) * NN + n0);
        float4 f1 = *(const float4*)(xb + (size_t)(c0 + 1) * NN + n0);
        float4 f2 = *(const float4*)(xb + (size_t)(c0 + 2) * NN + n0);
        float4 f3 = *(const float4*)(xb + (size_t)(c0 + 3) * NN + n0);
        // register 4x4 transpose + pack: n = n0+jn gets halfs k=c0..c0+3
        uint2 v0, v1, v2, v3;
        v0.x = cvt_pk_bf16(f0.x, f1.x); v0.y = cvt_pk_bf16(f2.x, f3.x);
        v1.x = cvt_pk_bf16(f0.y, f1.y); v1.y = cvt_pk_bf16(f2.y, f3.y);
        v2.x = cvt_pk_bf16(f0.z, f1.z); v2.y = cvt_pk_bf16(f2.z, f3.z);
        v3.x = cvt_pk_bf16(f0.w, f1.w); v3.y = cvt_pk_bf16(f2.w, f3.w);
        const int g0 = ((c0 >> 3) + n0) & 15;
        *(uint2*)&qT[(n0 + 0) * K3_LD + (((g0 + 0) & 15)) * 8 + (c0 & 7)] = v0;
        *(uint2*)&qT[(n0 + 1) * K3_LD + (((g0 + 1) & 15)) * 8 + (c0 & 7)] = v1;
        *(uint2*)&qT[(n0 + 2) * K3_LD + (((g0 + 2) & 15)) * 8 + (c0 & 7)] = v2;
        *(uint2*)&qT[(n0 + 3) * K3_LD + (((g0 + 3) & 15)) * 8 + (c0 & 7)] = v3;
    }
    __syncthreads();

    const int w = t >> 6, lane = t & 63, quad = lane >> 4, colL = lane & 15;
    const u16* ag = attb + (size_t)b * CC * CC;
    floatx4 acc[8][2];
#pragma unroll
    for (int rt = 0; rt < 8; ++rt) { acc[rt][0] = {0.f,0.f,0.f,0.f}; acc[rt][1] = {0.f,0.f,0.f,0.f}; }

#pragma unroll
    for (int ks = 0; ks < 4; ++ks) {
        const int kk = ks * 32 + quad * 8;
        const int n_a = w * 32 + colL;
        const int n_b = n_a + 16;
        short8 bf0 = *(const short8*)&qT[n_a * K3_LD + ((((kk) >> 3) + n_a) & 15) * 8];
        short8 bf1 = *(const short8*)&qT[n_b * K3_LD + ((((kk) >> 3) + n_b) & 15) * 8];
#pragma unroll
        for (int rt = 0; rt < 8; ++rt) {
            short8 af = *(const short8*)&ag[(rt * 16 + colL) * CC + kk];   // L1-hot
            acc[rt][0] = __builtin_amdgcn_mfma_f32_16x16x32_bf16(af, bf0, acc[rt][0], 0, 0, 0);
            acc[rt][1] = __builtin_amdgcn_mfma_f32_16x16x32_bf16(af, bf1, acc[rt][1], 0, 0, 0);
        }
    }

    float* ob = out + (size_t)b * CC * NN + nn0;
#pragma unroll
    for (int rt = 0; rt < 8; ++rt)
#pragma unroll
        for (int ct = 0; ct < 2; ++ct)
#pragma unroll
            for (int r = 0; r < 4; ++r) {
                int chn = rt * 16 + quad * 4 + r;
                int nn  = w * 32 + ct * 16 + colL;
                float v = alpha[chn] * acc[rt][ct][r] + beta[chn]
                        + xb[(size_t)chn * NN + nn];   // residual fp32 (L1-hot re-read)
                ob[(size_t)chn * NN + nn] = v;
            }
}

// ---------------------------------------------------------------------------
// ws layout (bytes):
//   [0,       1048576)  energy   fp32 [16][128][128]  (written by k_reduce)
//   [1048576, 1056768)  S        fp32 [16][128]       (zeroed)
//   [1056768, 1057280)  meanacc  fp32 [128]           (zeroed)
//   [1057280, 1057792)  e2acc    fp32 [128]           (zeroed)
//   [1057792, 1582080)  attb     bf16 [16][128][128]
//   [2097152, 35651584) partials fp32 [16][32][128][128] (plain stores)
// ---------------------------------------------------------------------------
extern "C" void kernel_launch(void* const* d_in, const int* in_sizes, int n_in,
                              void* d_out, int out_size, void* d_ws, size_t ws_size,
                              hipStream_t stream)
{
    const float* x     = (const float*)d_in[0];
    const float* gamma = (const float*)d_in[1];
    const float* bnw   = (const float*)d_in[2];
    const float* bnb   = (const float*)d_in[3];
    float* out = (float*)d_out;

    char* ws = (char*)d_ws;
    float* energy   = (float*)(ws);
    float* S        = (float*)(ws + 1048576);
    float* meanacc  = (float*)(ws + 1056768);
    float* e2acc    = (float*)(ws + 1057280);
    u16*   attb     = (u16*)(ws + 1057792);
    float* partials = (float*)(ws + 2097152);

    hipMemsetAsync(ws + 1048576, 0, 9216, stream);   // zero S/meanacc/e2acc only
    hipLaunchKernelGGL(k_gram,   dim3(512),  dim3(512), 0, stream, x, partials, S);
    hipLaunchKernelGGL(k_reduce, dim3(1024), dim3(256), 0, stream, partials, energy);
    hipLaunchKernelGGL(k_soft,   dim3(512),  dim3(256), 0, stream, energy, S, attb, meanacc, e2acc);
    hipLaunchKernelGGL(k_out,    dim3(2048), dim3(256), 0, stream, x, attb, meanacc, e2acc, gamma, bnw, bnb, out);
}